// Round 1
// baseline (710.229 us; speedup 1.0000x reference)
//
#include <hip/hip_runtime.h>
#include <hip/hip_bf16.h>

// Problem constants (from reference):
//   FILTERS=128, STRIDE=4, CHANNEL_MULTIPLIER=2, N_EVENTS=4194304, N_OUT=65536
// Output: [N_OUT, STRIDE*FILTERS*M] = [65536, 1024] float32 = 256 MiB.
// out[(seg*512 + id)*2 + m] += exp(-softplus(decay_rate[id&127][m]) * dt[e])

#define F 128
#define M 2
#define SF 512  // STRIDE * FILTERS

__global__ void __launch_bounds__(256)
onehot_scatter_kernel(const float* __restrict__ dt,
                      const float* __restrict__ decay_rate,
                      const int* __restrict__ kc_ids,
                      const int* __restrict__ seg_ids,
                      float* __restrict__ out,
                      int n_events) {
    // Stage softplus(decay_rate) in LDS: 128*2 floats.
    __shared__ float rate[F * M];
    for (int i = threadIdx.x; i < F * M; i += blockDim.x) {
        float x = decay_rate[i];
        // numerically-stable softplus (x ~ N(0,0.1) so plain form would be
        // fine too, but stability is free here)
        rate[i] = fmaxf(x, 0.0f) + log1pf(expf(-fabsf(x)));
    }
    __syncthreads();

    int stride = gridDim.x * blockDim.x;
    for (int e = blockIdx.x * blockDim.x + threadIdx.x; e < n_events; e += stride) {
        float d  = dt[e];
        int   id = kc_ids[e];
        int   sg = seg_ids[e];
        int   ch = id & (F - 1);            // id % FILTERS
        float r0 = rate[ch * M + 0];
        float r1 = rate[ch * M + 1];
        float v0 = expf(-r0 * d);
        float v1 = expf(-r1 * d);
        size_t o = ((size_t)sg * SF + (size_t)id) * M;
        atomicAdd(&out[o + 0], v0);
        atomicAdd(&out[o + 1], v1);
    }
}

extern "C" void kernel_launch(void* const* d_in, const int* in_sizes, int n_in,
                              void* d_out, int out_size, void* d_ws, size_t ws_size,
                              hipStream_t stream) {
    const float* dt         = (const float*)d_in[0];
    // d_in[1] = times_out — unused by the computation (only its length matters)
    const float* decay_rate = (const float*)d_in[2];
    const int*   kc_ids     = (const int*)d_in[3];
    const int*   seg_ids    = (const int*)d_in[4];
    float*       out        = (float*)d_out;

    int n_events = in_sizes[0];

    // Output is mostly zeros (4M events into 33.5M slots) — zero it first.
    hipMemsetAsync(d_out, 0, (size_t)out_size * sizeof(float), stream);

    int block = 256;
    int grid  = (n_events + block - 1) / block;  // 16384 blocks
    onehot_scatter_kernel<<<grid, block, 0, stream>>>(
        dt, decay_rate, kc_ids, seg_ids, out, n_events);
}